// Round 3
// baseline (1385.077 us; speedup 1.0000x reference)
//
#include <hip/hip_runtime.h>
#include <hip/hip_bf16.h>

// Problem constants (match reference: shape=[15,400,400], batch_size=2)
#define DD 15
#define HH 400
#define WW 400
#define CIN 32
#define COUT 64
#define KK 27
#define NVOX (2 * DD * HH * WW)        // 4,800,000
#define CAP 32768                       // per-k pair capacity (actual ~8.3k)

// ---------- init: table = -1, cnt = 0 -------------------------------------------------
__global__ void init_table_kernel(int* __restrict__ table, int* __restrict__ cnt) {
    int t = blockIdx.x * blockDim.x + threadIdx.x;
    if (t < KK) cnt[t] = 0;
    int stride = gridDim.x * blockDim.x;
    for (int i = t; i < NVOX; i += stride) table[i] = -1;
}

// ---------- fill: table[flat(coors[i])] = i -------------------------------------------
__global__ void fill_table_kernel(const int* __restrict__ coors,
                                  int* __restrict__ table, int n) {
    int i = blockIdx.x * blockDim.x + threadIdx.x;
    if (i >= n) return;
    int b = coors[i * 4 + 0];
    int z = coors[i * 4 + 1];
    int y = coors[i * 4 + 2];
    int x = coors[i * 4 + 3];
    table[((b * DD + z) * HH + y) * WW + x] = i;
}

// ---------- transpose weights: w[27][C][64] -> wt[27][64][C] --------------------------
__global__ void transpose_w_kernel(const float* __restrict__ w,
                                   float* __restrict__ wt, int C) {
    int t = blockIdx.x * blockDim.x + threadIdx.x;
    if (t >= KK * C * 64) return;
    int k = t / (C * 64);
    int r = t - k * C * 64;
    int c = r / 64;
    int o = r - c * 64;
    wt[((size_t)k * 64 + o) * C + c] = w[t];
}

// ---------- off-center pair lists, grouped by k ---------------------------------------
__global__ void build_pairs_kernel(const int* __restrict__ coors,
                                   const int* __restrict__ table,
                                   int* __restrict__ cnt,
                                   int* __restrict__ pairI,
                                   int* __restrict__ pairJ, int n) {
    int t = blockIdx.x * blockDim.x + threadIdx.x;
    if (t >= n * 9) return;
    int i = t / 9;
    int p = t - i * 9;                     // (dz+1)*3 + (dy+1)
    int dz = p / 3 - 1;
    int dy = p % 3 - 1;
    int b = coors[i * 4 + 0];
    int z = coors[i * 4 + 1] + dz;
    int y = coors[i * 4 + 2] + dy;
    int x = coors[i * 4 + 3];
    if (z < 0 || z >= DD || y < 0 || y >= HH) return;
    int f0 = ((b * DD + z) * HH + y) * WW + x;
    int kb = p * 3;                        // k = kb + (dx+1)
#pragma unroll
    for (int dx1 = 0; dx1 < 3; ++dx1) {    // dx = dx1-1
        int k = kb + dx1;
        if (k == 13) continue;             // center handled densely
        if (dx1 == 0 && x == 0) continue;
        if (dx1 == 2 && x == WW - 1) continue;
        int j = table[f0 + dx1 - 1];
        if (j < 0) continue;
        int pos = atomicAdd(&cnt[k], 1);
        if (pos < CAP) {
            pairI[k * CAP + pos] = i;
            pairJ[k * CAP + pos] = j;
        }
    }
}

// ---------- center tap: out[i] = x[i] @ W[13]  (dense, writes/initializes out) --------
// lane = cout; wave handles 16 voxels; weight column held in registers.
template <int C>
__global__ __launch_bounds__(256) void center_kernel(
        const float* __restrict__ xin, const float* __restrict__ wt13,
        float* __restrict__ xout, int n) {
    int lane = threadIdx.x & 63;
    int wave = blockIdx.x * 4 + (threadIdx.x >> 6);
    float w[C];
    const float4* wp = (const float4*)(wt13 + (size_t)lane * C);
#pragma unroll
    for (int c4 = 0; c4 < C / 4; ++c4) {
        float4 v = wp[c4];
        w[c4 * 4 + 0] = v.x; w[c4 * 4 + 1] = v.y;
        w[c4 * 4 + 2] = v.z; w[c4 * 4 + 3] = v.w;
    }
    int v0 = wave * 16;
    int vend = min(v0 + 16, n);
    for (int v = v0; v < vend; ++v) {
        const float4* xp = (const float4*)(xin + (size_t)v * C);
        float a0 = 0.f, a1 = 0.f, a2 = 0.f, a3 = 0.f;
#pragma unroll
        for (int c4 = 0; c4 < C / 4; ++c4) {
            float4 xv = xp[c4];
            a0 += xv.x * w[c4 * 4 + 0];
            a1 += xv.y * w[c4 * 4 + 1];
            a2 += xv.z * w[c4 * 4 + 2];
            a3 += xv.w * w[c4 * 4 + 3];
        }
        xout[(size_t)v * 64 + lane] = (a0 + a1) + (a2 + a3);
    }
}

// ---------- off-center taps: out[i] += x[j] @ W[k], k-grouped, weight-stationary ------
// grid = 27*256 blocks; block b: k = b>>8, chunk = b&255; wave handles 32 pairs.
template <int C>
__global__ __launch_bounds__(256) void offc_kernel(
        const float* __restrict__ xin, const float* __restrict__ wt,
        const int* __restrict__ cnt, const int* __restrict__ pairI,
        const int* __restrict__ pairJ, float* __restrict__ outp) {
    int lane = threadIdx.x & 63;
    int k = blockIdx.x >> 8;
    int chunk = blockIdx.x & 255;
    int ck = min(cnt[k], CAP);
    int m0 = chunk * 128 + ((threadIdx.x >> 6) << 5);
    if (m0 >= ck) return;
    int nit = min(32, ck - m0);
    int base = k * CAP + m0;
    int pi = pairI[base + (lane & 31)];
    int pj = pairJ[base + (lane & 31)];
    float w[C];
    const float4* wp = (const float4*)(wt + ((size_t)k * 64 + lane) * C);
#pragma unroll
    for (int c4 = 0; c4 < C / 4; ++c4) {
        float4 v = wp[c4];
        w[c4 * 4 + 0] = v.x; w[c4 * 4 + 1] = v.y;
        w[c4 * 4 + 2] = v.z; w[c4 * 4 + 3] = v.w;
    }
    for (int p = 0; p < nit; ++p) {
        int i_ = __shfl(pi, p);
        int j_ = __shfl(pj, p);
        const float4* xp = (const float4*)(xin + (size_t)j_ * C);
        float a0 = 0.f, a1 = 0.f, a2 = 0.f, a3 = 0.f;
#pragma unroll
        for (int c4 = 0; c4 < C / 4; ++c4) {
            float4 xv = xp[c4];
            a0 += xv.x * w[c4 * 4 + 0];
            a1 += xv.y * w[c4 * 4 + 1];
            a2 += xv.z * w[c4 * 4 + 2];
            a3 += xv.w * w[c4 * 4 + 3];
        }
        atomicAdd(outp + (size_t)i_ * 64 + lane, (a0 + a1) + (a2 + a3));
    }
}

extern "C" void kernel_launch(void* const* d_in, const int* in_sizes, int n_in,
                              void* d_out, int out_size, void* d_ws, size_t ws_size,
                              hipStream_t stream) {
    const float* feats = (const float*)d_in[0];   // [N,32] fp32
    const int*   coors = (const int*)d_in[1];     // [N,4] int32
    const float* W1 = (const float*)d_in[3];      // [27,32,64] fp32
    const float* W2 = (const float*)d_in[4];      // [27,64,64] fp32
    float* out = (float*)d_out;                   // [N,64] fp32

    int n = in_sizes[0] / CIN;                    // 200000

    // ws layout: regionA = table (phase 1) overlapped with x1 (phase 2) | Wt1 | Wt2 | cnt | pairI | pairJ
    char* ws = (char*)d_ws;
    size_t off = 0;
    size_t szA = (size_t)n * COUT * 4;            // 51.2 MB >= table's 19.2 MB
    if (szA < (size_t)NVOX * 4) szA = (size_t)NVOX * 4;
    int*   table = (int*)(ws + off);
    float* x1    = (float*)(ws + off);
    off += (szA + 255) & ~(size_t)255;
    float* Wt1 = (float*)(ws + off);
    off += ((size_t)KK * CIN * COUT * 4 + 255) & ~(size_t)255;
    float* Wt2 = (float*)(ws + off);
    off += ((size_t)KK * COUT * COUT * 4 + 255) & ~(size_t)255;
    int* cnt = (int*)(ws + off);
    off += 256;
    int* pairI = (int*)(ws + off);
    off += ((size_t)KK * CAP * 4 + 4096 + 255) & ~(size_t)255;  // +pad for tail reads
    int* pairJ = (int*)(ws + off);

    init_table_kernel<<<4096, 256, 0, stream>>>(table, cnt);
    fill_table_kernel<<<(n + 255) / 256, 256, 0, stream>>>(coors, table, n);
    transpose_w_kernel<<<(KK * CIN * COUT + 255) / 256, 256, 0, stream>>>(W1, Wt1, CIN);
    transpose_w_kernel<<<(KK * COUT * COUT + 255) / 256, 256, 0, stream>>>(W2, Wt2, COUT);
    build_pairs_kernel<<<(n * 9 + 255) / 256, 256, 0, stream>>>(coors, table, cnt,
                                                                pairI, pairJ, n);
    // layer 1: feats [N,32] -> x1 [N,64]
    center_kernel<CIN><<<(n + 63) / 64, 256, 0, stream>>>(
        feats, Wt1 + (size_t)13 * 64 * CIN, x1, n);
    offc_kernel<CIN><<<KK * 256, 256, 0, stream>>>(feats, Wt1, cnt, pairI, pairJ, x1);
    // layer 2: x1 [N,64] -> out [N,64]
    center_kernel<COUT><<<(n + 63) / 64, 256, 0, stream>>>(
        x1, Wt2 + (size_t)13 * 64 * COUT, out, n);
    offc_kernel<COUT><<<KK * 256, 256, 0, stream>>>(x1, Wt2, cnt, pairI, pairJ, out);
}

// Round 4
// 547.295 us; speedup vs baseline: 2.5308x; 2.5308x over previous
//
#include <hip/hip_runtime.h>
#include <hip/hip_bf16.h>

// Problem constants (match reference: shape=[15,400,400], batch_size=2)
#define DD 15
#define HH 400
#define WW 400
#define CIN 32
#define COUT 64
#define KK 27
#define NVOX (2 * DD * HH * WW)        // 4,800,000
#define CAP 32768                       // per-k pair capacity (actual ~8.3k)
#define CNT_STRIDE 64                   // one counter per 256B line (atomic contention fix)

// ---------- init: table = -1, cnt = 0 -------------------------------------------------
__global__ void init_table_kernel(int* __restrict__ table, int* __restrict__ cnt) {
    int t = blockIdx.x * blockDim.x + threadIdx.x;
    if (t < KK * CNT_STRIDE) cnt[t] = 0;
    int stride = gridDim.x * blockDim.x;
    for (int i = t; i < NVOX; i += stride) table[i] = -1;
}

// ---------- fill: table[flat(coors[i])] = i -------------------------------------------
__global__ void fill_table_kernel(const int* __restrict__ coors,
                                  int* __restrict__ table, int n) {
    int i = blockIdx.x * blockDim.x + threadIdx.x;
    if (i >= n) return;
    int b = coors[i * 4 + 0];
    int z = coors[i * 4 + 1];
    int y = coors[i * 4 + 2];
    int x = coors[i * 4 + 3];
    table[((b * DD + z) * HH + y) * WW + x] = i;
}

// ---------- transpose weights: w[27][C][64] -> wt[27][64][C] --------------------------
__global__ void transpose_w_kernel(const float* __restrict__ w,
                                   float* __restrict__ wt, int C) {
    int t = blockIdx.x * blockDim.x + threadIdx.x;
    if (t >= KK * C * 64) return;
    int k = t / (C * 64);
    int r = t - k * C * 64;
    int c = r / 64;
    int o = r - c * 64;
    wt[((size_t)k * 64 + o) * C + c] = w[t];
}

// ---------- off-center pair lists, grouped by k (LDS-aggregated reservations) ---------
__global__ __launch_bounds__(256) void build_pairs_kernel(
        const int* __restrict__ coors, const int* __restrict__ table,
        int* __restrict__ cnt, int* __restrict__ pairI,
        int* __restrict__ pairJ, int n) {
    __shared__ int lcnt[KK];
    __shared__ int lbase[KK];
    int t = blockIdx.x * blockDim.x + threadIdx.x;
    if (threadIdx.x < KK) lcnt[threadIdx.x] = 0;
    __syncthreads();

    int jj0 = -1, jj1 = -1, jj2 = -1;     // candidate neighbor rows for dx=-1,0,+1
    int lp0 = 0, lp1 = 0, lp2 = 0;        // local positions within block's k-bucket
    int i = 0, kb = 0;
    if (t < n * 9) {
        i = t / 9;
        int p = t - i * 9;                // (dz+1)*3 + (dy+1)
        kb = p * 3;
        int dz = p / 3 - 1;
        int dy = p % 3 - 1;
        int b = coors[i * 4 + 0];
        int z = coors[i * 4 + 1] + dz;
        int y = coors[i * 4 + 2] + dy;
        int x = coors[i * 4 + 3];
        if (z >= 0 && z < DD && y >= 0 && y < HH) {
            int f0 = ((b * DD + z) * HH + y) * WW + x;
            if (x > 0) {
                int j = table[f0 - 1];
                if (j >= 0) { jj0 = j; lp0 = atomicAdd(&lcnt[kb + 0], 1); }
            }
            if (kb + 1 != 13) {           // center handled densely
                int j = table[f0];
                if (j >= 0) { jj1 = j; lp1 = atomicAdd(&lcnt[kb + 1], 1); }
            }
            if (x < WW - 1) {
                int j = table[f0 + 1];
                if (j >= 0) { jj2 = j; lp2 = atomicAdd(&lcnt[kb + 2], 1); }
            }
        }
    }
    __syncthreads();
    if (threadIdx.x < KK && lcnt[threadIdx.x] > 0)
        lbase[threadIdx.x] = atomicAdd(&cnt[threadIdx.x * CNT_STRIDE], lcnt[threadIdx.x]);
    __syncthreads();
    if (jj0 >= 0) {
        int pos = lbase[kb + 0] + lp0;
        if (pos < CAP) { pairI[(kb + 0) * CAP + pos] = i; pairJ[(kb + 0) * CAP + pos] = jj0; }
    }
    if (jj1 >= 0) {
        int pos = lbase[kb + 1] + lp1;
        if (pos < CAP) { pairI[(kb + 1) * CAP + pos] = i; pairJ[(kb + 1) * CAP + pos] = jj1; }
    }
    if (jj2 >= 0) {
        int pos = lbase[kb + 2] + lp2;
        if (pos < CAP) { pairI[(kb + 2) * CAP + pos] = i; pairJ[(kb + 2) * CAP + pos] = jj2; }
    }
}

// ---------- center tap: out[i] = x[i] @ W[13]  (dense, writes/initializes out) --------
// lane = cout; wave handles 16 voxels; weight column held in registers.
template <int C>
__global__ __launch_bounds__(256) void center_kernel(
        const float* __restrict__ xin, const float* __restrict__ wt13,
        float* __restrict__ xout, int n) {
    int lane = threadIdx.x & 63;
    int wave = blockIdx.x * 4 + (threadIdx.x >> 6);
    float w[C];
    const float4* wp = (const float4*)(wt13 + (size_t)lane * C);
#pragma unroll
    for (int c4 = 0; c4 < C / 4; ++c4) {
        float4 v = wp[c4];
        w[c4 * 4 + 0] = v.x; w[c4 * 4 + 1] = v.y;
        w[c4 * 4 + 2] = v.z; w[c4 * 4 + 3] = v.w;
    }
    int v0 = wave * 16;
    int vend = min(v0 + 16, n);
    for (int v = v0; v < vend; ++v) {
        const float4* xp = (const float4*)(xin + (size_t)v * C);
        float a0 = 0.f, a1 = 0.f, a2 = 0.f, a3 = 0.f;
#pragma unroll
        for (int c4 = 0; c4 < C / 4; ++c4) {
            float4 xv = xp[c4];
            a0 += xv.x * w[c4 * 4 + 0];
            a1 += xv.y * w[c4 * 4 + 1];
            a2 += xv.z * w[c4 * 4 + 2];
            a3 += xv.w * w[c4 * 4 + 3];
        }
        xout[(size_t)v * 64 + lane] = (a0 + a1) + (a2 + a3);
    }
}

// ---------- off-center taps: out[i] += x[j] @ W[k], k-grouped, weight-stationary ------
// grid = 27*256 blocks; block b: k = b>>8, chunk = b&255; wave handles 32 pairs.
template <int C>
__global__ __launch_bounds__(256) void offc_kernel(
        const float* __restrict__ xin, const float* __restrict__ wt,
        const int* __restrict__ cnt, const int* __restrict__ pairI,
        const int* __restrict__ pairJ, float* __restrict__ outp) {
    int lane = threadIdx.x & 63;
    int k = blockIdx.x >> 8;
    int chunk = blockIdx.x & 255;
    int ck = min(cnt[k * CNT_STRIDE], CAP);
    int m0 = chunk * 128 + ((threadIdx.x >> 6) << 5);
    if (m0 >= ck) return;
    int nit = min(32, ck - m0);
    int base = k * CAP + m0;
    int pi = pairI[base + (lane & 31)];
    int pj = pairJ[base + (lane & 31)];
    float w[C];
    const float4* wp = (const float4*)(wt + ((size_t)k * 64 + lane) * C);
#pragma unroll
    for (int c4 = 0; c4 < C / 4; ++c4) {
        float4 v = wp[c4];
        w[c4 * 4 + 0] = v.x; w[c4 * 4 + 1] = v.y;
        w[c4 * 4 + 2] = v.z; w[c4 * 4 + 3] = v.w;
    }
    for (int p = 0; p < nit; ++p) {
        int i_ = __shfl(pi, p);
        int j_ = __shfl(pj, p);
        const float4* xp = (const float4*)(xin + (size_t)j_ * C);
        float a0 = 0.f, a1 = 0.f, a2 = 0.f, a3 = 0.f;
#pragma unroll
        for (int c4 = 0; c4 < C / 4; ++c4) {
            float4 xv = xp[c4];
            a0 += xv.x * w[c4 * 4 + 0];
            a1 += xv.y * w[c4 * 4 + 1];
            a2 += xv.z * w[c4 * 4 + 2];
            a3 += xv.w * w[c4 * 4 + 3];
        }
        atomicAdd(outp + (size_t)i_ * 64 + lane, (a0 + a1) + (a2 + a3));
    }
}

extern "C" void kernel_launch(void* const* d_in, const int* in_sizes, int n_in,
                              void* d_out, int out_size, void* d_ws, size_t ws_size,
                              hipStream_t stream) {
    const float* feats = (const float*)d_in[0];   // [N,32] fp32
    const int*   coors = (const int*)d_in[1];     // [N,4] int32
    const float* W1 = (const float*)d_in[3];      // [27,32,64] fp32
    const float* W2 = (const float*)d_in[4];      // [27,64,64] fp32
    float* out = (float*)d_out;                   // [N,64] fp32

    int n = in_sizes[0] / CIN;                    // 200000

    // ws layout: regionA = table (phase 1) overlapped with x1 (phase 2) | Wt1 | Wt2 | cnt | pairI | pairJ
    char* ws = (char*)d_ws;
    size_t off = 0;
    size_t szA = (size_t)n * COUT * 4;            // 51.2 MB >= table's 19.2 MB
    if (szA < (size_t)NVOX * 4) szA = (size_t)NVOX * 4;
    int*   table = (int*)(ws + off);
    float* x1    = (float*)(ws + off);
    off += (szA + 255) & ~(size_t)255;
    float* Wt1 = (float*)(ws + off);
    off += ((size_t)KK * CIN * COUT * 4 + 255) & ~(size_t)255;
    float* Wt2 = (float*)(ws + off);
    off += ((size_t)KK * COUT * COUT * 4 + 255) & ~(size_t)255;
    int* cnt = (int*)(ws + off);
    off += ((size_t)KK * CNT_STRIDE * 4 + 255) & ~(size_t)255;
    int* pairI = (int*)(ws + off);
    off += ((size_t)KK * CAP * 4 + 4096 + 255) & ~(size_t)255;  // +pad for tail reads
    int* pairJ = (int*)(ws + off);

    init_table_kernel<<<4096, 256, 0, stream>>>(table, cnt);
    fill_table_kernel<<<(n + 255) / 256, 256, 0, stream>>>(coors, table, n);
    transpose_w_kernel<<<(KK * CIN * COUT + 255) / 256, 256, 0, stream>>>(W1, Wt1, CIN);
    transpose_w_kernel<<<(KK * COUT * COUT + 255) / 256, 256, 0, stream>>>(W2, Wt2, COUT);
    build_pairs_kernel<<<(n * 9 + 255) / 256, 256, 0, stream>>>(coors, table, cnt,
                                                                pairI, pairJ, n);
    // layer 1: feats [N,32] -> x1 [N,64]
    center_kernel<CIN><<<(n + 63) / 64, 256, 0, stream>>>(
        feats, Wt1 + (size_t)13 * 64 * CIN, x1, n);
    offc_kernel<CIN><<<KK * 256, 256, 0, stream>>>(feats, Wt1, cnt, pairI, pairJ, x1);
    // layer 2: x1 [N,64] -> out [N,64]
    center_kernel<COUT><<<(n + 63) / 64, 256, 0, stream>>>(
        x1, Wt2 + (size_t)13 * 64 * COUT, out, n);
    offc_kernel<COUT><<<KK * 256, 256, 0, stream>>>(x1, Wt2, cnt, pairI, pairJ, out);
}

// Round 5
// 451.730 us; speedup vs baseline: 3.0662x; 1.2116x over previous
//
#include <hip/hip_runtime.h>
#include <hip/hip_bf16.h>

// Problem constants (match reference: shape=[15,400,400], batch_size=2)
#define DD 15
#define HH 400
#define WW 400
#define CIN 32
#define COUT 64
#define KK 27
#define NVOX (2 * DD * HH * WW)        // 4,800,000
#define CAP 32768                       // per-k pair capacity (actual ~8.3k)
#define CNT_STRIDE 64                   // one counter per 256B line
#define OFFC_GRID 2048

// ---------- init: table = -1, cnt = 0 -------------------------------------------------
__global__ void init_table_kernel(int* __restrict__ table, int* __restrict__ cnt) {
    int t = blockIdx.x * blockDim.x + threadIdx.x;
    if (t < KK * CNT_STRIDE) cnt[t] = 0;
    int stride = gridDim.x * blockDim.x;
    for (int i = t; i < NVOX; i += stride) table[i] = -1;
}

// ---------- fill: table[flat(coors[i])] = i -------------------------------------------
__global__ void fill_table_kernel(const int* __restrict__ coors,
                                  int* __restrict__ table, int n) {
    int i = blockIdx.x * blockDim.x + threadIdx.x;
    if (i >= n) return;
    int b = coors[i * 4 + 0];
    int z = coors[i * 4 + 1];
    int y = coors[i * 4 + 2];
    int x = coors[i * 4 + 3];
    table[((b * DD + z) * HH + y) * WW + x] = i;
}

// ---------- transpose weights: w[27][C][64] -> wt[27][64][C] --------------------------
__global__ void transpose_w_kernel(const float* __restrict__ w,
                                   float* __restrict__ wt, int C) {
    int t = blockIdx.x * blockDim.x + threadIdx.x;
    if (t >= KK * C * 64) return;
    int k = t / (C * 64);
    int r = t - k * C * 64;
    int c = r / 64;
    int o = r - c * 64;
    wt[((size_t)k * 64 + o) * C + c] = w[t];
}

// ---------- off-center pair lists, grouped by k (LDS-aggregated reservations) ---------
__global__ __launch_bounds__(256) void build_pairs_kernel(
        const int* __restrict__ coors, const int* __restrict__ table,
        int* __restrict__ cnt, int* __restrict__ pairI,
        int* __restrict__ pairJ, int n) {
    __shared__ int lcnt[KK];
    __shared__ int lbase[KK];
    int t = blockIdx.x * blockDim.x + threadIdx.x;
    if (threadIdx.x < KK) lcnt[threadIdx.x] = 0;
    __syncthreads();

    int jj0 = -1, jj1 = -1, jj2 = -1;
    int lp0 = 0, lp1 = 0, lp2 = 0;
    int i = 0, kb = 0;
    if (t < n * 9) {
        i = t / 9;
        int p = t - i * 9;                // (dz+1)*3 + (dy+1)
        kb = p * 3;
        int dz = p / 3 - 1;
        int dy = p % 3 - 1;
        int b = coors[i * 4 + 0];
        int z = coors[i * 4 + 1] + dz;
        int y = coors[i * 4 + 2] + dy;
        int x = coors[i * 4 + 3];
        if (z >= 0 && z < DD && y >= 0 && y < HH) {
            int f0 = ((b * DD + z) * HH + y) * WW + x;
            if (x > 0) {
                int j = table[f0 - 1];
                if (j >= 0) { jj0 = j; lp0 = atomicAdd(&lcnt[kb + 0], 1); }
            }
            if (kb + 1 != 13) {
                int j = table[f0];
                if (j >= 0) { jj1 = j; lp1 = atomicAdd(&lcnt[kb + 1], 1); }
            }
            if (x < WW - 1) {
                int j = table[f0 + 1];
                if (j >= 0) { jj2 = j; lp2 = atomicAdd(&lcnt[kb + 2], 1); }
            }
        }
    }
    __syncthreads();
    if (threadIdx.x < KK && lcnt[threadIdx.x] > 0)
        lbase[threadIdx.x] = atomicAdd(&cnt[threadIdx.x * CNT_STRIDE], lcnt[threadIdx.x]);
    __syncthreads();
    if (jj0 >= 0) {
        int pos = lbase[kb + 0] + lp0;
        if (pos < CAP) { pairI[(kb + 0) * CAP + pos] = i; pairJ[(kb + 0) * CAP + pos] = jj0; }
    }
    if (jj1 >= 0) {
        int pos = lbase[kb + 1] + lp1;
        if (pos < CAP) { pairI[(kb + 1) * CAP + pos] = i; pairJ[(kb + 1) * CAP + pos] = jj1; }
    }
    if (jj2 >= 0) {
        int pos = lbase[kb + 2] + lp2;
        if (pos < CAP) { pairI[(kb + 2) * CAP + pos] = i; pairJ[(kb + 2) * CAP + pos] = jj2; }
    }
}

// ---------- pad each k-list to a multiple of 128 with sentinel pairs ------------------
__global__ void pad_pairs_kernel(const int* __restrict__ cnt,
                                 int* __restrict__ pairI,
                                 int* __restrict__ pairJ, int n) {
    int k = blockIdx.x;
    int ck = min(cnt[k * CNT_STRIDE], CAP);
    int ckp = min((ck + 127) & ~127, CAP);
    for (int pos = ck + (int)threadIdx.x; pos < ckp; pos += blockDim.x) {
        pairI[k * CAP + pos] = n;      // sentinel: offc guard skips the atomic
        pairJ[k * CAP + pos] = 0;      // valid row, read is harmless
    }
}

// ---------- center tap: out[i] = x[i] @ W[13]  (dense, writes/initializes out) --------
template <int C>
__global__ __launch_bounds__(256) void center_kernel(
        const float* __restrict__ xin, const float* __restrict__ wt13,
        float* __restrict__ xout, int n) {
    int lane = threadIdx.x & 63;
    int wave = blockIdx.x * 4 + (threadIdx.x >> 6);
    float w[C];
    const float4* wp = (const float4*)(wt13 + (size_t)lane * C);
#pragma unroll
    for (int c4 = 0; c4 < C / 4; ++c4) {
        float4 v = wp[c4];
        w[c4 * 4 + 0] = v.x; w[c4 * 4 + 1] = v.y;
        w[c4 * 4 + 2] = v.z; w[c4 * 4 + 3] = v.w;
    }
    auto body = [&](int v) {
        const float4* xp = (const float4*)(xin + (size_t)v * C);
        float a0 = 0.f, a1 = 0.f, a2 = 0.f, a3 = 0.f;
#pragma unroll
        for (int c4 = 0; c4 < C / 4; ++c4) {
            float4 xv = xp[c4];
            a0 += xv.x * w[c4 * 4 + 0];
            a1 += xv.y * w[c4 * 4 + 1];
            a2 += xv.z * w[c4 * 4 + 2];
            a3 += xv.w * w[c4 * 4 + 3];
        }
        xout[(size_t)v * 64 + lane] = (a0 + a1) + (a2 + a3);
    };
    int v0 = wave * 16;
    if (v0 + 16 <= n) {
#pragma unroll 2
        for (int v = v0; v < v0 + 16; ++v) body(v);
    } else {
        for (int v = v0; v < n; ++v) body(v);
    }
}

// ---------- off-center taps: out[i] += x[j] @ W[k] ------------------------------------
// Pipelined: coalesced coop-load of x-row -> per-wave LDS row -> broadcast ds_read;
// 2-pair global-load lookahead; dynamic (k,chunk) assignment; constant 32-trip loop.
template <int C>
__global__ __launch_bounds__(256) void offc_kernel(
        const float* __restrict__ xin, const float* __restrict__ wt,
        const int* __restrict__ cnt, const int* __restrict__ pairI,
        const int* __restrict__ pairJ, float* __restrict__ outp, int n) {
    __shared__ float rb[4][64];
    __shared__ int pfx[KK + 1];
    int lane = threadIdx.x & 63;
    int wid = threadIdx.x >> 6;
    if (threadIdx.x == 0) {
        int acc = 0; pfx[0] = 0;
        for (int k = 0; k < KK; ++k) {
            int ck = min(cnt[k * CNT_STRIDE], CAP);
            acc += (ck + 127) >> 7;               // chunks of 128 pairs
            pfx[k + 1] = acc;
        }
    }
    __syncthreads();
    int T = pfx[KK];
    float* buf = rb[wid];
    for (int g = blockIdx.x; g < T; g += gridDim.x) {
        int k = 0;
        while (pfx[k + 1] <= g) ++k;
        int chunk = g - pfx[k];
        float w[C];
        const float4* wp = (const float4*)(wt + ((size_t)k * 64 + lane) * C);
#pragma unroll
        for (int c4 = 0; c4 < C / 4; ++c4) {
            float4 v = wp[c4];
            w[c4 * 4 + 0] = v.x; w[c4 * 4 + 1] = v.y;
            w[c4 * 4 + 2] = v.z; w[c4 * 4 + 3] = v.w;
        }
        int base = k * CAP + chunk * 128 + wid * 32;
        int pi = pairI[base + (lane & 31)];
        int pj = pairJ[base + (lane & 31)];
        float v0 = 0.f, v1 = 0.f;
        int j_;
        j_ = __shfl(pj, 0); if (lane < C) v0 = xin[(size_t)j_ * C + lane];
        j_ = __shfl(pj, 1); if (lane < C) v1 = xin[(size_t)j_ * C + lane];
        for (int p = 0; p < 32; p += 2) {
            // ---- even pair p (row in v0) ----
            if (lane < C) buf[lane] = v0;
            if (p + 2 < 32) { j_ = __shfl(pj, p + 2); if (lane < C) v0 = xin[(size_t)j_ * C + lane]; }
            {
                const float4* rp = (const float4*)buf;
                float a0 = 0.f, a1 = 0.f, a2 = 0.f, a3 = 0.f;
#pragma unroll
                for (int c4 = 0; c4 < C / 4; ++c4) {
                    float4 xv = rp[c4];
                    a0 += xv.x * w[c4 * 4 + 0];
                    a1 += xv.y * w[c4 * 4 + 1];
                    a2 += xv.z * w[c4 * 4 + 2];
                    a3 += xv.w * w[c4 * 4 + 3];
                }
                int i_ = __shfl(pi, p);
                if (i_ < n) atomicAdd(outp + (size_t)i_ * 64 + lane, (a0 + a1) + (a2 + a3));
            }
            // ---- odd pair p+1 (row in v1) ----
            if (lane < C) buf[lane] = v1;
            if (p + 3 < 32) { j_ = __shfl(pj, p + 3); if (lane < C) v1 = xin[(size_t)j_ * C + lane]; }
            {
                const float4* rp = (const float4*)buf;
                float a0 = 0.f, a1 = 0.f, a2 = 0.f, a3 = 0.f;
#pragma unroll
                for (int c4 = 0; c4 < C / 4; ++c4) {
                    float4 xv = rp[c4];
                    a0 += xv.x * w[c4 * 4 + 0];
                    a1 += xv.y * w[c4 * 4 + 1];
                    a2 += xv.z * w[c4 * 4 + 2];
                    a3 += xv.w * w[c4 * 4 + 3];
                }
                int i_ = __shfl(pi, p + 1);
                if (i_ < n) atomicAdd(outp + (size_t)i_ * 64 + lane, (a0 + a1) + (a2 + a3));
            }
        }
    }
}

extern "C" void kernel_launch(void* const* d_in, const int* in_sizes, int n_in,
                              void* d_out, int out_size, void* d_ws, size_t ws_size,
                              hipStream_t stream) {
    const float* feats = (const float*)d_in[0];   // [N,32] fp32
    const int*   coors = (const int*)d_in[1];     // [N,4] int32
    const float* W1 = (const float*)d_in[3];      // [27,32,64] fp32
    const float* W2 = (const float*)d_in[4];      // [27,64,64] fp32
    float* out = (float*)d_out;                   // [N,64] fp32

    int n = in_sizes[0] / CIN;                    // 200000

    // ws layout: regionA = table (phase 1) overlapped with x1 (phase 2) | Wt1 | Wt2 | cnt | pairI | pairJ
    char* ws = (char*)d_ws;
    size_t off = 0;
    size_t szA = (size_t)n * COUT * 4;            // 51.2 MB >= table's 19.2 MB
    if (szA < (size_t)NVOX * 4) szA = (size_t)NVOX * 4;
    int*   table = (int*)(ws + off);
    float* x1    = (float*)(ws + off);
    off += (szA + 255) & ~(size_t)255;
    float* Wt1 = (float*)(ws + off);
    off += ((size_t)KK * CIN * COUT * 4 + 255) & ~(size_t)255;
    float* Wt2 = (float*)(ws + off);
    off += ((size_t)KK * COUT * COUT * 4 + 255) & ~(size_t)255;
    int* cnt = (int*)(ws + off);
    off += ((size_t)KK * CNT_STRIDE * 4 + 255) & ~(size_t)255;
    int* pairI = (int*)(ws + off);
    off += ((size_t)KK * CAP * 4 + 4096 + 255) & ~(size_t)255;
    int* pairJ = (int*)(ws + off);

    init_table_kernel<<<4096, 256, 0, stream>>>(table, cnt);
    fill_table_kernel<<<(n + 255) / 256, 256, 0, stream>>>(coors, table, n);
    transpose_w_kernel<<<(KK * CIN * COUT + 255) / 256, 256, 0, stream>>>(W1, Wt1, CIN);
    transpose_w_kernel<<<(KK * COUT * COUT + 255) / 256, 256, 0, stream>>>(W2, Wt2, COUT);
    build_pairs_kernel<<<(n * 9 + 255) / 256, 256, 0, stream>>>(coors, table, cnt,
                                                                pairI, pairJ, n);
    pad_pairs_kernel<<<KK, 256, 0, stream>>>(cnt, pairI, pairJ, n);
    // layer 1: feats [N,32] -> x1 [N,64]
    center_kernel<CIN><<<(n + 63) / 64, 256, 0, stream>>>(
        feats, Wt1 + (size_t)13 * 64 * CIN, x1, n);
    offc_kernel<CIN><<<OFFC_GRID, 256, 0, stream>>>(feats, Wt1, cnt, pairI, pairJ, x1, n);
    // layer 2: x1 [N,64] -> out [N,64]
    center_kernel<COUT><<<(n + 63) / 64, 256, 0, stream>>>(
        x1, Wt2 + (size_t)13 * 64 * COUT, out, n);
    offc_kernel<COUT><<<OFFC_GRID, 256, 0, stream>>>(x1, Wt2, cnt, pairI, pairJ, out, n);
}

// Round 6
// 215.231 us; speedup vs baseline: 6.4353x; 2.0988x over previous
//
#include <hip/hip_runtime.h>
#include <hip/hip_bf16.h>

// Problem constants (match reference: shape=[15,400,400], batch_size=2)
#define DD 15
#define HH 400
#define WW 400
#define CIN 32
#define COUT 64
#define KK 27
#define NVOX (2 * DD * HH * WW)        // 4,800,000
#define CAP 32768                       // per-k pair capacity (actual ~8.3k), mult of 128
#define CNT_STRIDE 64                   // one counter per 256B line
#define OFFC_GRID 2048

typedef short bf16x8 __attribute__((ext_vector_type(8)));
typedef float f32x4  __attribute__((ext_vector_type(4)));

__device__ inline short f2bf(float f) {               // f32 -> bf16 RNE
    unsigned u = __float_as_uint(f);
    return (short)((u + 0x7FFFu + ((u >> 16) & 1u)) >> 16);
}

// ---------- init: table = -1, cnt = 0 -------------------------------------------------
__global__ void init_table_kernel(int* __restrict__ table, int* __restrict__ cnt) {
    int t = blockIdx.x * blockDim.x + threadIdx.x;
    if (t < KK * CNT_STRIDE) cnt[t] = 0;
    int stride = gridDim.x * blockDim.x;
    for (int i = t; i < NVOX; i += stride) table[i] = -1;
}

// ---------- fill: table[flat(coors[i])] = i -------------------------------------------
__global__ void fill_table_kernel(const int* __restrict__ coors,
                                  int* __restrict__ table, int n) {
    int i = blockIdx.x * blockDim.x + threadIdx.x;
    if (i >= n) return;
    int b = coors[i * 4 + 0];
    int z = coors[i * 4 + 1];
    int y = coors[i * 4 + 2];
    int x = coors[i * 4 + 3];
    table[((b * DD + z) * HH + y) * WW + x] = i;
}

// ---------- off-center pair lists, grouped by k (LDS-aggregated reservations) ---------
__global__ __launch_bounds__(256) void build_pairs_kernel(
        const int* __restrict__ coors, const int* __restrict__ table,
        int* __restrict__ cnt, int* __restrict__ pairI,
        int* __restrict__ pairJ, int n) {
    __shared__ int lcnt[KK];
    __shared__ int lbase[KK];
    int t = blockIdx.x * blockDim.x + threadIdx.x;
    if (threadIdx.x < KK) lcnt[threadIdx.x] = 0;
    __syncthreads();

    int jj0 = -1, jj1 = -1, jj2 = -1;
    int lp0 = 0, lp1 = 0, lp2 = 0;
    int i = 0, kb = 0;
    if (t < n * 9) {
        i = t / 9;
        int p = t - i * 9;                // (dz+1)*3 + (dy+1)
        kb = p * 3;
        int dz = p / 3 - 1;
        int dy = p % 3 - 1;
        int b = coors[i * 4 + 0];
        int z = coors[i * 4 + 1] + dz;
        int y = coors[i * 4 + 2] + dy;
        int x = coors[i * 4 + 3];
        if (z >= 0 && z < DD && y >= 0 && y < HH) {
            int f0 = ((b * DD + z) * HH + y) * WW + x;
            if (x > 0) {
                int j = table[f0 - 1];
                if (j >= 0) { jj0 = j; lp0 = atomicAdd(&lcnt[kb + 0], 1); }
            }
            if (kb + 1 != 13) {
                int j = table[f0];
                if (j >= 0) { jj1 = j; lp1 = atomicAdd(&lcnt[kb + 1], 1); }
            }
            if (x < WW - 1) {
                int j = table[f0 + 1];
                if (j >= 0) { jj2 = j; lp2 = atomicAdd(&lcnt[kb + 2], 1); }
            }
        }
    }
    __syncthreads();
    if (threadIdx.x < KK && lcnt[threadIdx.x] > 0)
        lbase[threadIdx.x] = atomicAdd(&cnt[threadIdx.x * CNT_STRIDE], lcnt[threadIdx.x]);
    __syncthreads();
    if (jj0 >= 0) {
        int pos = lbase[kb + 0] + lp0;
        if (pos < CAP) { pairI[(kb + 0) * CAP + pos] = i; pairJ[(kb + 0) * CAP + pos] = jj0; }
    }
    if (jj1 >= 0) {
        int pos = lbase[kb + 1] + lp1;
        if (pos < CAP) { pairI[(kb + 1) * CAP + pos] = i; pairJ[(kb + 1) * CAP + pos] = jj1; }
    }
    if (jj2 >= 0) {
        int pos = lbase[kb + 2] + lp2;
        if (pos < CAP) { pairI[(kb + 2) * CAP + pos] = i; pairJ[(kb + 2) * CAP + pos] = jj2; }
    }
}

// ---------- pad each k-list to a multiple of 128 with sentinel pairs ------------------
__global__ void pad_pairs_kernel(const int* __restrict__ cnt,
                                 int* __restrict__ pairI,
                                 int* __restrict__ pairJ, int n) {
    int k = blockIdx.x;
    int ck = min(cnt[k * CNT_STRIDE], CAP);
    int ckp = min((ck + 127) & ~127, CAP);
    for (int pos = ck + (int)threadIdx.x; pos < ckp; pos += blockDim.x) {
        pairI[k * CAP + pos] = n;      // sentinel: skip store
        pairJ[k * CAP + pos] = 0;      // valid row, read harmless
    }
}

// ---------- center tap (MFMA): out[i] = x[i] @ W[13], dense, writes/initializes ------
// Per 16-row m-tile: A = x rows (bf16), B = W13 fragments (held in regs), 16x16x32 MFMA.
// A k-index and B k-index use the SAME lane function -> any hidden k-permutation cancels.
template <int C>
__global__ __launch_bounds__(256) void center_mfma_kernel(
        const float* __restrict__ xin, const float* __restrict__ Wc,  // Wc = W + 13*C*64
        float* __restrict__ xout, int n) {
    constexpr int KT = C / 32;
    int lane = threadIdx.x & 63;
    int mrow = lane & 15;            // A row / B col / D col
    int kgrp = lane >> 4;            // k-group (8 k's per group)
    int wid = (blockIdx.x * blockDim.x + threadIdx.x) >> 6;
    int nwaves = (gridDim.x * blockDim.x) >> 6;

    bf16x8 bf[KT][4];                // B fragments: [k-tile][n-tile]
#pragma unroll
    for (int kt = 0; kt < KT; ++kt)
#pragma unroll
        for (int nt = 0; nt < 4; ++nt)
#pragma unroll
            for (int j = 0; j < 8; ++j)
                bf[kt][nt][j] = f2bf(Wc[(kt * 32 + kgrp * 8 + j) * 64 + nt * 16 + mrow]);

    int ntiles = (n + 15) >> 4;
    for (int t = wid; t < ntiles; t += nwaves) {
        int row = t * 16 + mrow;
        f32x4 zero = {0.f, 0.f, 0.f, 0.f};
        bf16x8 a[KT];
        if (row < n) {
            const float* xr = xin + (size_t)row * C + kgrp * 8;
#pragma unroll
            for (int kt = 0; kt < KT; ++kt) {
                float4 x0 = *(const float4*)(xr + kt * 32);
                float4 x1 = *(const float4*)(xr + kt * 32 + 4);
                a[kt][0] = f2bf(x0.x); a[kt][1] = f2bf(x0.y);
                a[kt][2] = f2bf(x0.z); a[kt][3] = f2bf(x0.w);
                a[kt][4] = f2bf(x1.x); a[kt][5] = f2bf(x1.y);
                a[kt][6] = f2bf(x1.z); a[kt][7] = f2bf(x1.w);
            }
        } else {
#pragma unroll
            for (int kt = 0; kt < KT; ++kt)
#pragma unroll
                for (int j = 0; j < 8; ++j) a[kt][j] = 0;
        }
        f32x4 acc[4];
#pragma unroll
        for (int nt = 0; nt < 4; ++nt) {
            acc[nt] = zero;
#pragma unroll
            for (int kt = 0; kt < KT; ++kt)
                acc[nt] = __builtin_amdgcn_mfma_f32_16x16x32_bf16(a[kt], bf[kt][nt], acc[nt], 0, 0, 0);
        }
        // D: col = mrow, row = kgrp*4 + r
#pragma unroll
        for (int nt = 0; nt < 4; ++nt)
#pragma unroll
            for (int r = 0; r < 4; ++r) {
                int orow = t * 16 + kgrp * 4 + r;
                if (orow < n)
                    xout[(size_t)orow * 64 + nt * 16 + mrow] = acc[nt][r];
            }
    }
}

// ---------- off-center taps (MFMA): out[pairI] += x[pairJ] @ W[k] ---------------------
// Dynamic (k, chunk-of-128) assignment; per wave 2 m-tiles of 16 pairs.
template <int C>
__global__ __launch_bounds__(256) void offc_mfma_kernel(
        const float* __restrict__ xin, const float* __restrict__ Wsrc,
        const int* __restrict__ cnt, const int* __restrict__ pairI,
        const int* __restrict__ pairJ, float* __restrict__ outp, int n) {
    constexpr int KT = C / 32;
    __shared__ int pfx[KK + 1];
    int lane = threadIdx.x & 63;
    int wid = threadIdx.x >> 6;
    int mrow = lane & 15;
    int kgrp = lane >> 4;
    if (threadIdx.x == 0) {
        int acc = 0; pfx[0] = 0;
        for (int k = 0; k < KK; ++k) {
            int ck = min(cnt[k * CNT_STRIDE], CAP);
            acc += (ck + 127) >> 7;
            pfx[k + 1] = acc;
        }
    }
    __syncthreads();
    int T = pfx[KK];
    for (int g = blockIdx.x; g < T; g += gridDim.x) {
        int k = 0;
        while (pfx[k + 1] <= g) ++k;
        int chunk = g - pfx[k];
        const float* Wk = Wsrc + (size_t)k * C * 64;
        bf16x8 bf[KT][4];
#pragma unroll
        for (int kt = 0; kt < KT; ++kt)
#pragma unroll
            for (int nt = 0; nt < 4; ++nt)
#pragma unroll
                for (int j = 0; j < 8; ++j)
                    bf[kt][nt][j] = f2bf(Wk[(kt * 32 + kgrp * 8 + j) * 64 + nt * 16 + mrow]);
        int base = k * CAP + chunk * 128 + wid * 32;
#pragma unroll
        for (int half = 0; half < 2; ++half) {
            int b16 = base + half * 16;
            int jrow = pairJ[b16 + mrow];                  // sentinel -> row 0, harmless
            const float* xr = xin + (size_t)jrow * C + kgrp * 8;
            bf16x8 a[KT];
#pragma unroll
            for (int kt = 0; kt < KT; ++kt) {
                float4 x0 = *(const float4*)(xr + kt * 32);
                float4 x1 = *(const float4*)(xr + kt * 32 + 4);
                a[kt][0] = f2bf(x0.x); a[kt][1] = f2bf(x0.y);
                a[kt][2] = f2bf(x0.z); a[kt][3] = f2bf(x0.w);
                a[kt][4] = f2bf(x1.x); a[kt][5] = f2bf(x1.y);
                a[kt][6] = f2bf(x1.z); a[kt][7] = f2bf(x1.w);
            }
            f32x4 zero = {0.f, 0.f, 0.f, 0.f};
            f32x4 acc[4];
#pragma unroll
            for (int nt = 0; nt < 4; ++nt) {
                acc[nt] = zero;
#pragma unroll
                for (int kt = 0; kt < KT; ++kt)
                    acc[nt] = __builtin_amdgcn_mfma_f32_16x16x32_bf16(a[kt], bf[kt][nt], acc[nt], 0, 0, 0);
            }
            int irow[4];
#pragma unroll
            for (int r = 0; r < 4; ++r) irow[r] = pairI[b16 + kgrp * 4 + r];
#pragma unroll
            for (int nt = 0; nt < 4; ++nt)
#pragma unroll
                for (int r = 0; r < 4; ++r)
                    if (irow[r] < n)
                        atomicAdd(outp + (size_t)irow[r] * 64 + nt * 16 + mrow, acc[nt][r]);
        }
    }
}

extern "C" void kernel_launch(void* const* d_in, const int* in_sizes, int n_in,
                              void* d_out, int out_size, void* d_ws, size_t ws_size,
                              hipStream_t stream) {
    const float* feats = (const float*)d_in[0];   // [N,32] fp32
    const int*   coors = (const int*)d_in[1];     // [N,4] int32
    const float* W1 = (const float*)d_in[3];      // [27,32,64] fp32
    const float* W2 = (const float*)d_in[4];      // [27,64,64] fp32
    float* out = (float*)d_out;                   // [N,64] fp32

    int n = in_sizes[0] / CIN;                    // 200000

    // ws layout: regionA = table (phase 1) overlapped with x1 (phase 2) | cnt | pairI | pairJ
    char* ws = (char*)d_ws;
    size_t off = 0;
    size_t szA = (size_t)n * COUT * 4;            // 51.2 MB >= table's 19.2 MB
    if (szA < (size_t)NVOX * 4) szA = (size_t)NVOX * 4;
    int*   table = (int*)(ws + off);
    float* x1    = (float*)(ws + off);
    off += (szA + 255) & ~(size_t)255;
    int* cnt = (int*)(ws + off);
    off += ((size_t)KK * CNT_STRIDE * 4 + 255) & ~(size_t)255;
    int* pairI = (int*)(ws + off);
    off += ((size_t)KK * CAP * 4 + 4096 + 255) & ~(size_t)255;
    int* pairJ = (int*)(ws + off);

    init_table_kernel<<<4096, 256, 0, stream>>>(table, cnt);
    fill_table_kernel<<<(n + 255) / 256, 256, 0, stream>>>(coors, table, n);
    build_pairs_kernel<<<(n * 9 + 255) / 256, 256, 0, stream>>>(coors, table, cnt,
                                                                pairI, pairJ, n);
    pad_pairs_kernel<<<KK, 256, 0, stream>>>(cnt, pairI, pairJ, n);
    // layer 1: feats [N,32] -> x1 [N,64]
    center_mfma_kernel<CIN><<<784, 256, 0, stream>>>(
        feats, W1 + (size_t)13 * CIN * COUT, x1, n);
    offc_mfma_kernel<CIN><<<OFFC_GRID, 256, 0, stream>>>(feats, W1, cnt, pairI, pairJ, x1, n);
    // layer 2: x1 [N,64] -> out [N,64]
    center_mfma_kernel<COUT><<<784, 256, 0, stream>>>(
        x1, W2 + (size_t)13 * COUT * COUT, out, n);
    offc_mfma_kernel<COUT><<<OFFC_GRID, 256, 0, stream>>>(x1, W2, cnt, pairI, pairJ, out, n);
}